// Round 9
// baseline (298.064 us; speedup 1.0000x reference)
//
#include <hip/hip_runtime.h>

#define DIMM 2048
#define SEQ 2048
#define NHEAD 32
#define NKV 8
#define QKV_N 3072   // (32 + 2*8) * 64
#define NQ 4096      // BATCH * SEQ

typedef short bfrag __attribute__((ext_vector_type(8)));   // 8 bf16 = 4 VGPR (MFMA A/B)
typedef short h4 __attribute__((ext_vector_type(4)));      // 4 bf16 = 8B
typedef float ffrag __attribute__((ext_vector_type(4)));   // 4 f32 accumulator
typedef unsigned short u16;

__device__ inline u16 f2bf(float f) {
    union { float f; unsigned int u; } v; v.f = f;
    unsigned int r = (v.u + 0x7FFFu + ((v.u >> 16) & 1u)) >> 16;
    return (u16)r;
}
// pack two non-negative floats to bf16 pair (round-half-up; p>=0 here)
__device__ inline unsigned int pack2(float a, float b) {
    union { float f; unsigned int u; } x, y; x.f = a; y.f = b;
    return ((x.u + 0x8000u) >> 16) | ((y.u + 0x8000u) & 0xFFFF0000u);
}

// ---------------- fp32 -> bf16 bulk convert (one-time pre-pass) ----------------
__global__ void cvt_bf16(const float* __restrict__ src, u16* __restrict__ dst, int n) {
    int i = (blockIdx.x * blockDim.x + threadIdx.x) * 4;
    if (i < n) {
        float4 v = *(const float4*)(src + i);
        h4 o;
        o[0] = (short)f2bf(v.x); o[1] = (short)f2bf(v.y);
        o[2] = (short)f2bf(v.z); o[3] = (short)f2bf(v.w);
        *(h4*)(dst + i) = o;
    }
}

// async global->LDS, 16B per lane; LDS dest is wave-uniform base + lane*16 (HW rule)
__device__ inline void gl_lds16(const u16* g, u16* l) {
    __builtin_amdgcn_global_load_lds(
        (const __attribute__((address_space(1))) unsigned int*)g,
        (__attribute__((address_space(3))) unsigned int*)l, 16, 0, 0);
}

// Stage R x 64 bf16 tile (row stride gstride elems) into LDS via global_load_lds.
// XOR swizzle: LDS chunk p of row r holds global chunk p^(r&7).
template<int R>
__device__ inline void stage64(const u16* __restrict__ g, int gstride, u16* lds) {
    int tid = threadIdx.x, w = tid >> 6, l = tid & 63;
#pragma unroll
    for (int i = 0; i < R / 32; ++i) {
        int row = w * (R / 4) + i * 8 + (l >> 3);
        int c = (l & 7) ^ (row & 7);
        gl_lds16(g + (size_t)row * gstride + c * 8, lds + (w * (R / 4) + i * 8) * 64);
    }
}

__device__ inline bfrag frag64(const u16* lds, int row, int ch) {
    return *(const bfrag*)(lds + row * 64 + (ch ^ (row & 7)) * 8);
}

// ---------------- NT GEMM v2: double-buffered pipeline ----------------
// C[M][N] = A[M][K] @ B[N][K]^T, bf16 in, fp32 accum. 128x128 tile, BK=64.
// Prefetch tile k+1 issued BEFORE computing tile k; single barrier per k-iter
// drains the prefetch after ~600 cyc of compute (attn-r5-proven shape).
// LDS: 2x16KB (A) + 2x16KB (B) = 64 KB -> 2 blocks/CU (m132 precedent for 64KB).
template<bool CF32, bool SCALEQ>
__global__ __launch_bounds__(256, 2) void gemm_nt(const u16* __restrict__ A,
                                                  const u16* __restrict__ B,
                                                  void* __restrict__ Cp, int M, int N, int K) {
    __shared__ u16 As[2][128 * 64];
    __shared__ u16 Bs[2][128 * 64];
    int tid = threadIdx.x, lane = tid & 63, w = tid >> 6;
    int quad = lane >> 4, n16 = lane & 15;
    int wm = w >> 1, wn = w & 1;
    int m0 = blockIdx.y * 128, n0 = blockIdx.x * 128;

    int nk = K >> 6;
    stage64<128>(A + (size_t)m0 * K, K, As[0]);
    stage64<128>(B + (size_t)n0 * K, K, Bs[0]);
    __syncthreads();

    ffrag acc[4][4] = {};
    for (int i = 0; i < nk; ++i) {
        int cur = i & 1;
        if (i + 1 < nk) {  // issue next-tile prefetch before compute (drain lands late)
            stage64<128>(A + (size_t)m0 * K + (i + 1) * 64, K, As[cur ^ 1]);
            stage64<128>(B + (size_t)n0 * K + (i + 1) * 64, K, Bs[cur ^ 1]);
        }
        const u16* as = As[cur];
        const u16* bs = Bs[cur];
#pragma unroll
        for (int ks = 0; ks < 2; ++ks) {
            bfrag a[4], b[4];
#pragma unroll
            for (int t = 0; t < 4; ++t) a[t] = frag64(as, wm * 64 + t * 16 + n16, ks * 4 + quad);
#pragma unroll
            for (int t = 0; t < 4; ++t) b[t] = frag64(bs, wn * 64 + t * 16 + n16, ks * 4 + quad);
#pragma unroll
            for (int ti = 0; ti < 4; ++ti)
#pragma unroll
                for (int tj = 0; tj < 4; ++tj)
                    acc[ti][tj] = __builtin_amdgcn_mfma_f32_16x16x32_bf16(a[ti], b[tj], acc[ti][tj], 0, 0, 0);
        }
        __syncthreads();  // drains prefetch (after compute) + guards buffer reuse
    }
    // C/D layout: col = lane&15, row = quad*4 + r
#pragma unroll
    for (int ti = 0; ti < 4; ++ti) {
        int row = m0 + wm * 64 + ti * 16 + quad * 4;
#pragma unroll
        for (int tj = 0; tj < 4; ++tj) {
            int col = n0 + wn * 64 + tj * 16 + n16;
            float sc = (SCALEQ && col < NHEAD * 64) ? 0.125f : 1.0f;
#pragma unroll
            for (int r = 0; r < 4; ++r) {
                if (CF32) ((float*)Cp)[(size_t)(row + r) * N + col] = acc[ti][tj][r];
                else      ((u16*)Cp)[(size_t)(row + r) * N + col] = f2bf(acc[ti][tj][r] * sc);
            }
        }
    }
}

// ---------------- V transpose: Vt[(b*8+kh)*64 + d][s] = qkv[b*SEQ+s][(40+kh)*64 + d] ---
__global__ void transpose_v(const u16* __restrict__ qkv, u16* __restrict__ vt) {
    __shared__ u16 t[64][72];
    int b = blockIdx.z, kh = blockIdx.y, s0 = blockIdx.x * 64;
    int tid = threadIdx.x;
    {
        int r = tid >> 2, c = tid & 3;
        const u16* gp = qkv + (size_t)(b * SEQ + s0 + r) * QKV_N + (NHEAD + NKV + kh) * 64 + c * 16;
        *(bfrag*)&t[r][c * 16] = *(const bfrag*)gp;
        *(bfrag*)&t[r][c * 16 + 8] = *(const bfrag*)(gp + 8);
    }
    __syncthreads();
    {
        int d = tid >> 2, c = tid & 3;
        u16* op = vt + (size_t)((b * 8 + kh) * 64 + d) * SEQ + s0 + c * 16;
        bfrag v0, v1;
#pragma unroll
        for (int j = 0; j < 8; ++j) ((u16*)&v0)[j] = t[c * 16 + j][d];
#pragma unroll
        for (int j = 0; j < 8; ++j) ((u16*)&v1)[j] = t[c * 16 + 8 + j][d];
        *(bfrag*)op = v0;
        *(bfrag*)(op + 8) = v1;
    }
}

// ---------------- Flash attention v5 (unchanged from round 8) ----------------
// Balanced causal pairing + 1-deep software pipeline: iteration i runs S^T(i) and
// PV(i-1); P(i-1) read into regs at top (same-wave in-order DS). V staged lag-1.
// LDS: 16K (K) + 16K (V) + 18K (Ps) = 50 KB.
#define LDP 72  // Ps row stride (u16)

template<bool MASKED>
__device__ inline void st_phase(int kb, int rowbase, int quad, int n16, int wrow,
                                const bfrag qf[2][2], const u16* Ks, u16* Ps, float* lsum) {
#pragma unroll
    for (int tj = 0; tj < 4; ++tj) {
        bfrag kf0 = frag64(Ks, tj * 16 + n16, quad);
        bfrag kf1 = frag64(Ks, tj * 16 + n16, 4 + quad);
        ffrag st[2] = {};
#pragma unroll
        for (int ti = 0; ti < 2; ++ti) {
            st[ti] = __builtin_amdgcn_mfma_f32_16x16x32_bf16(kf0, qf[ti][0], st[ti], 0, 0, 0);
            st[ti] = __builtin_amdgcn_mfma_f32_16x16x32_bf16(kf1, qf[ti][1], st[ti], 0, 0, 0);
        }
        int key0 = kb * 64 + tj * 16 + quad * 4;  // this lane's 4 consecutive keys
#pragma unroll
        for (int ti = 0; ti < 2; ++ti) {
            int qrow = rowbase + ti * 16 + n16;   // global q row (col of S^T tile)
            float p[4];
#pragma unroll
            for (int r = 0; r < 4; ++r) {
                float e = __expf(st[ti][r]);
                if (MASKED && (key0 + r > qrow)) e = 0.f;
                p[r] = e;
                lsum[ti] += e;
            }
            uint2 pk; pk.x = pack2(p[0], p[1]); pk.y = pack2(p[2], p[3]);
            *(uint2*)(Ps + (wrow + ti * 16 + n16) * LDP + tj * 16 + quad * 4) = pk;
        }
    }
}

__device__ inline void pv_phase(const bfrag pf[4], const u16* Vs, ffrag o[2][4],
                                int quad, int n16) {
#pragma unroll
    for (int ks = 0; ks < 2; ++ks) {
        bfrag vf[4];
#pragma unroll
        for (int dj = 0; dj < 4; ++dj) vf[dj] = frag64(Vs, dj * 16 + n16, ks * 4 + quad);
#pragma unroll
        for (int ti = 0; ti < 2; ++ti)
#pragma unroll
            for (int dj = 0; dj < 4; ++dj)
                o[ti][dj] = __builtin_amdgcn_mfma_f32_16x16x32_bf16(pf[ks * 2 + ti], vf[dj], o[ti][dj], 0, 0, 0);
    }
}

__global__ __launch_bounds__(256, 2) void attn(const u16* __restrict__ qkv,
                                               const u16* __restrict__ vt,
                                               u16* __restrict__ aout) {
    __shared__ u16 Ks[2][64 * 64];
    __shared__ u16 Vs[2][64 * 64];
    __shared__ u16 Ps[128 * LDP];

    int tid = threadIdx.x, lane = tid & 63, w = tid >> 6;
    int quad = lane >> 4, n16 = lane & 15;
    int pr = blockIdx.x;  // pair index 0..7
    int h = blockIdx.y, b = blockIdx.z;
    int kh = h & 7;  // jnp.tile semantics: kv head = h % NKV
    int wrow = w * 32;  // wave's local row base in Ps

    const u16* Qg = qkv + (size_t)(b * SEQ) * QKV_N + h * 64;  // pre-scaled by 1/8
    const u16* Kg = qkv + (size_t)(b * SEQ) * QKV_N + (NHEAD + kh) * 64;
    const u16* Vg = vt + (size_t)((b * 8 + kh) * 64) * SEQ;

#pragma unroll
    for (int half = 0; half < 2; ++half) {
        int qb = half ? pr : (15 - pr);  // heavy q-block first
        int q0 = qb * 128;
        int rowbase = q0 + wrow;

        // Q fragments straight from global (B-operand layout: n16 = q-row, quad = d-chunk)
        bfrag qf[2][2];
#pragma unroll
        for (int ti = 0; ti < 2; ++ti)
#pragma unroll
            for (int ks = 0; ks < 2; ++ks)
                qf[ti][ks] = *(const bfrag*)(Qg + (size_t)(rowbase + ti * 16 + n16) * QKV_N + ks * 32 + quad * 8);

        ffrag o[2][4] = {};
        float lsum[2] = {0.f, 0.f};
        bfrag pf[4];

        int nkb = 2 * qb + 2;  // 64-key blocks covering keys <= q0+127
        stage64<64>(Kg, QKV_N, Ks[0]);
        __syncthreads();
        for (int i = 0; i <= nkb; ++i) {
            // prefetch: K one block ahead, V for the current S^T block (lag-1 consumer)
            if (i + 1 < nkb) stage64<64>(Kg + (size_t)((i + 1) * 64) * QKV_N, QKV_N, Ks[(i + 1) & 1]);
            if (i < nkb)     stage64<64>(Vg + i * 64, SEQ, Vs[i & 1]);
            if (i > 0) {
                // read P(i-1) into regs — written last iteration, no lgkm stall
#pragma unroll
                for (int ks = 0; ks < 2; ++ks)
#pragma unroll
                    for (int ti = 0; ti < 2; ++ti)
                        pf[ks * 2 + ti] = *(const bfrag*)(Ps + (wrow + ti * 16 + n16) * LDP + ks * 32 + quad * 8);
            }
            if (i < nkb) {
                if (i >= nkb - 2) st_phase<true>(i, rowbase, quad, n16, wrow, qf, Ks[i & 1], Ps, lsum);
                else              st_phase<false>(i, rowbase, quad, n16, wrow, qf, Ks[i & 1], Ps, lsum);
            }
            if (i > 0) pv_phase(pf, Vs[(i - 1) & 1], o, quad, n16);
            __syncthreads();  // drains prefetch (after compute) + guards buffer reuse
        }

        // reduce l across quads (lanes sharing n16), then redistribute to C-layout rows
#pragma unroll
        for (int ti = 0; ti < 2; ++ti) {
            lsum[ti] += __shfl_xor(lsum[ti], 16, 64);
            lsum[ti] += __shfl_xor(lsum[ti], 32, 64);
        }
#pragma unroll
        for (int ti = 0; ti < 2; ++ti) {
#pragma unroll
            for (int r = 0; r < 4; ++r) {
                float inv = 1.f / __shfl(lsum[ti], quad * 4 + r, 64);
                size_t rg = (size_t)(b * SEQ + rowbase + ti * 16 + quad * 4 + r) * DIMM + h * 64;
#pragma unroll
                for (int dj = 0; dj < 4; ++dj)
                    aout[rg + dj * 16 + n16] = f2bf(o[ti][dj][r] * inv);
            }
        }
    }
}

extern "C" void kernel_launch(void* const* d_in, const int* in_sizes, int n_in,
                              void* d_out, int out_size, void* d_ws, size_t ws_size,
                              hipStream_t stream) {
    const float* x    = (const float*)d_in[0];  // [4096][2048] fp32
    const float* Wqkv = (const float*)d_in[1];  // [3072][2048] fp32
    const float* Wout = (const float*)d_in[2];  // [2048][2048] fp32
    // d_in[3] = mask (fp32): causal applied analytically in-kernel
    float* out = (float*)d_out;                 // [4096][2048] fp32

    // Workspace (52 MiB), aliased by sequential lifetime:
    //   qkv      [0, 24 MiB)                — live GEMM1 .. attn
    //   xb/aout  [24, 40 MiB)               — xb: cvt..GEMM1; aout: attn..GEMM2
    //   R        [40, 52 MiB)               — Wqkvb: cvt..GEMM1; then vt (4 MiB) + Woutb (8 MiB)
    u16* qkv   = (u16*)d_ws;
    u16* xb    = qkv + (size_t)NQ * QKV_N;
    u16* aout  = xb;
    u16* R     = xb + (size_t)NQ * DIMM;
    u16* Wqkvb = R;
    u16* vtb   = R;
    u16* Woutb = R + (size_t)2 * NKV * 64 * SEQ;

    dim3 blk(256);
    cvt_bf16<<<NQ * DIMM / 1024, blk, 0, stream>>>(x, xb, NQ * DIMM);
    cvt_bf16<<<QKV_N * DIMM / 1024, blk, 0, stream>>>(Wqkv, Wqkvb, QKV_N * DIMM);
    gemm_nt<false, true><<<dim3(QKV_N / 128, NQ / 128), blk, 0, stream>>>(xb, Wqkvb, qkv, NQ, QKV_N, DIMM);
    transpose_v<<<dim3(SEQ / 64, NKV, 2), blk, 0, stream>>>(qkv, vtb);
    cvt_bf16<<<DIMM * DIMM / 1024, blk, 0, stream>>>(Wout, Woutb, DIMM * DIMM);
    attn<<<dim3(8, NHEAD, 2), blk, 0, stream>>>(qkv, vtb, aout);
    gemm_nt<true, false><<<dim3(DIMM / 128, NQ / 128), blk, 0, stream>>>(aout, Woutb, out, NQ, DIMM, DIMM);
}

// Round 10
// 285.045 us; speedup vs baseline: 1.0457x; 1.0457x over previous
//
#include <hip/hip_runtime.h>

#define DIMM 2048
#define SEQ 2048
#define NHEAD 32
#define NKV 8
#define QKV_N 3072   // (32 + 2*8) * 64
#define NQ 4096      // BATCH * SEQ

typedef short bfrag __attribute__((ext_vector_type(8)));   // 8 bf16 = 4 VGPR (MFMA A/B)
typedef short h4 __attribute__((ext_vector_type(4)));      // 4 bf16 = 8B
typedef float ffrag __attribute__((ext_vector_type(4)));   // 4 f32 accumulator
typedef unsigned short u16;

__device__ inline u16 f2bf(float f) {
    union { float f; unsigned int u; } v; v.f = f;
    unsigned int r = (v.u + 0x7FFFu + ((v.u >> 16) & 1u)) >> 16;
    return (u16)r;
}
// pack two non-negative floats to bf16 pair (round-half-up; p>=0 here)
__device__ inline unsigned int pack2(float a, float b) {
    union { float f; unsigned int u; } x, y; x.f = a; y.f = b;
    return ((x.u + 0x8000u) >> 16) | ((y.u + 0x8000u) & 0xFFFF0000u);
}

__device__ inline void cvt4(const float* __restrict__ src, u16* __restrict__ dst, int i) {
    float4 v = *(const float4*)(src + i);
    h4 o;
    o[0] = (short)f2bf(v.x); o[1] = (short)f2bf(v.y);
    o[2] = (short)f2bf(v.z); o[3] = (short)f2bf(v.w);
    *(h4*)(dst + i) = o;
}

// ---------------- fused fp32->bf16 convert: x (8,388,608 f) + Wqkv (6,291,456 f) ----
// Segment boundary at thread 2,097,152 = block 8192 — no intra-block divergence.
__global__ void cvt_xw(const float* __restrict__ x, u16* __restrict__ xb,
                       const float* __restrict__ w, u16* __restrict__ wb) {
    int t = blockIdx.x * blockDim.x + threadIdx.x;
    if (t < 2097152) cvt4(x, xb, t * 4);
    else             cvt4(w, wb, (t - 2097152) * 4);
}

// async global->LDS, 16B per lane; LDS dest is wave-uniform base + lane*16 (HW rule)
__device__ inline void gl_lds16(const u16* g, u16* l) {
    __builtin_amdgcn_global_load_lds(
        (const __attribute__((address_space(1))) unsigned int*)g,
        (__attribute__((address_space(3))) unsigned int*)l, 16, 0, 0);
}

// Stage R x 64 bf16 tile (row stride gstride elems) into LDS via global_load_lds.
// XOR swizzle: LDS chunk p of row r holds global chunk p^(r&7). Conflict-free
// (SQ_LDS_BANK_CONFLICT = 0 measured round 9).
template<int R>
__device__ inline void stage64(const u16* __restrict__ g, int gstride, u16* lds) {
    int tid = threadIdx.x, w = tid >> 6, l = tid & 63;
#pragma unroll
    for (int i = 0; i < R / 32; ++i) {
        int row = w * (R / 4) + i * 8 + (l >> 3);
        int c = (l & 7) ^ (row & 7);
        gl_lds16(g + (size_t)row * gstride + c * 8, lds + (w * (R / 4) + i * 8) * 64);
    }
}

__device__ inline bfrag frag64(const u16* lds, int row, int ch) {
    return *(const bfrag*)(lds + row * 64 + (ch ^ (row & 7)) * 8);
}

// ---------------- NT GEMM (m97 single-buffer — round-8 form, reverted from dbuf) ----
// C[M][N] = A[M][K] @ B[N][K]^T, bf16 in, fp32 accum. 128x128 tile, BK=64.
// LDS 36 KB; __launch_bounds__(256,3) -> 3 blocks/CU (dbuf regressed: m132 pattern,
// 64KB LDS cut occupancy; cross-block overlap beats in-block pipelining here).
template<bool CF32, bool SCALEQ>
__global__ __launch_bounds__(256, 3) void gemm_nt(const u16* __restrict__ A,
                                                  const u16* __restrict__ B,
                                                  void* __restrict__ Cp, int M, int N, int K) {
    __shared__ u16 As[128 * 64];
    __shared__ u16 Bs[128 * 64];
    int tid = threadIdx.x, lane = tid & 63, w = tid >> 6;
    int quad = lane >> 4, n16 = lane & 15;
    int wm = w >> 1, wn = w & 1;
    int m0 = blockIdx.y * 128, n0 = blockIdx.x * 128;

    ffrag acc[4][4] = {};
    for (int k0 = 0; k0 < K; k0 += 64) {
        stage64<128>(A + (size_t)m0 * K + k0, K, As);
        stage64<128>(B + (size_t)n0 * K + k0, K, Bs);
        __syncthreads();
#pragma unroll
        for (int ks = 0; ks < 2; ++ks) {
            bfrag a[4], b[4];
#pragma unroll
            for (int t = 0; t < 4; ++t) a[t] = frag64(As, wm * 64 + t * 16 + n16, ks * 4 + quad);
#pragma unroll
            for (int t = 0; t < 4; ++t) b[t] = frag64(Bs, wn * 64 + t * 16 + n16, ks * 4 + quad);
#pragma unroll
            for (int ti = 0; ti < 4; ++ti)
#pragma unroll
                for (int tj = 0; tj < 4; ++tj)
                    acc[ti][tj] = __builtin_amdgcn_mfma_f32_16x16x32_bf16(a[ti], b[tj], acc[ti][tj], 0, 0, 0);
        }
        __syncthreads();
    }
    // C/D layout: col = lane&15, row = quad*4 + r
#pragma unroll
    for (int ti = 0; ti < 4; ++ti) {
        int row = m0 + wm * 64 + ti * 16 + quad * 4;
#pragma unroll
        for (int tj = 0; tj < 4; ++tj) {
            int col = n0 + wn * 64 + tj * 16 + n16;
            float sc = (SCALEQ && col < NHEAD * 64) ? 0.125f : 1.0f;
#pragma unroll
            for (int r = 0; r < 4; ++r) {
                if (CF32) ((float*)Cp)[(size_t)(row + r) * N + col] = acc[ti][tj][r];
                else      ((u16*)Cp)[(size_t)(row + r) * N + col] = f2bf(acc[ti][tj][r] * sc);
            }
        }
    }
}

// ---------------- fused post-GEMM1 pass: cvt(Wout) + V transpose ----------------
// Blocks [0,4096): convert Wout (4,194,304 floats, 4/thread).
// Blocks [4096,4608): Vt[(b*8+kh)*64 + d][s] = qkv[b*SEQ+s][(40+kh)*64 + d].
// Whole blocks take one path — no divergence.
__global__ void post_gemm1(const u16* __restrict__ qkv, u16* __restrict__ vt,
                           const float* __restrict__ Wout, u16* __restrict__ Woutb) {
    __shared__ u16 t[64][72];
    int bid = blockIdx.x, tid = threadIdx.x;
    if (bid < 4096) {
        cvt4(Wout, Woutb, (bid * 256 + tid) * 4);
        return;
    }
    int idx = bid - 4096;
    int s0 = (idx & 31) * 64, kh = (idx >> 5) & 7, b = idx >> 8;
    {
        int r = tid >> 2, c = tid & 3;
        const u16* gp = qkv + (size_t)(b * SEQ + s0 + r) * QKV_N + (NHEAD + NKV + kh) * 64 + c * 16;
        *(bfrag*)&t[r][c * 16] = *(const bfrag*)gp;
        *(bfrag*)&t[r][c * 16 + 8] = *(const bfrag*)(gp + 8);
    }
    __syncthreads();
    {
        int d = tid >> 2, c = tid & 3;
        u16* op = vt + (size_t)((b * 8 + kh) * 64 + d) * SEQ + s0 + c * 16;
        bfrag v0, v1;
#pragma unroll
        for (int j = 0; j < 8; ++j) ((u16*)&v0)[j] = t[c * 16 + j][d];
#pragma unroll
        for (int j = 0; j < 8; ++j) ((u16*)&v1)[j] = t[c * 16 + 8 + j][d];
        *(bfrag*)op = v0;
        *(bfrag*)(op + 8) = v1;
    }
}

// ---------------- Flash attention v5 (unchanged from round 8: 68 µs) ----------------
// Balanced causal pairing + 1-deep software pipeline: iteration i runs S^T(i) and
// PV(i-1); P(i-1) read into regs at top (same-wave in-order DS). V staged lag-1.
// LDS: 16K (K) + 16K (V) + 18K (Ps) = 50 KB.
#define LDP 72  // Ps row stride (u16)

template<bool MASKED>
__device__ inline void st_phase(int kb, int rowbase, int quad, int n16, int wrow,
                                const bfrag qf[2][2], const u16* Ks, u16* Ps, float* lsum) {
#pragma unroll
    for (int tj = 0; tj < 4; ++tj) {
        bfrag kf0 = frag64(Ks, tj * 16 + n16, quad);
        bfrag kf1 = frag64(Ks, tj * 16 + n16, 4 + quad);
        ffrag st[2] = {};
#pragma unroll
        for (int ti = 0; ti < 2; ++ti) {
            st[ti] = __builtin_amdgcn_mfma_f32_16x16x32_bf16(kf0, qf[ti][0], st[ti], 0, 0, 0);
            st[ti] = __builtin_amdgcn_mfma_f32_16x16x32_bf16(kf1, qf[ti][1], st[ti], 0, 0, 0);
        }
        int key0 = kb * 64 + tj * 16 + quad * 4;  // this lane's 4 consecutive keys
#pragma unroll
        for (int ti = 0; ti < 2; ++ti) {
            int qrow = rowbase + ti * 16 + n16;   // global q row (col of S^T tile)
            float p[4];
#pragma unroll
            for (int r = 0; r < 4; ++r) {
                float e = __expf(st[ti][r]);
                if (MASKED && (key0 + r > qrow)) e = 0.f;
                p[r] = e;
                lsum[ti] += e;
            }
            uint2 pk; pk.x = pack2(p[0], p[1]); pk.y = pack2(p[2], p[3]);
            *(uint2*)(Ps + (wrow + ti * 16 + n16) * LDP + tj * 16 + quad * 4) = pk;
        }
    }
}

__device__ inline void pv_phase(const bfrag pf[4], const u16* Vs, ffrag o[2][4],
                                int quad, int n16) {
#pragma unroll
    for (int ks = 0; ks < 2; ++ks) {
        bfrag vf[4];
#pragma unroll
        for (int dj = 0; dj < 4; ++dj) vf[dj] = frag64(Vs, dj * 16 + n16, ks * 4 + quad);
#pragma unroll
        for (int ti = 0; ti < 2; ++ti)
#pragma unroll
            for (int dj = 0; dj < 4; ++dj)
                o[ti][dj] = __builtin_amdgcn_mfma_f32_16x16x32_bf16(pf[ks * 2 + ti], vf[dj], o[ti][dj], 0, 0, 0);
    }
}

__global__ __launch_bounds__(256, 2) void attn(const u16* __restrict__ qkv,
                                               const u16* __restrict__ vt,
                                               u16* __restrict__ aout) {
    __shared__ u16 Ks[2][64 * 64];
    __shared__ u16 Vs[2][64 * 64];
    __shared__ u16 Ps[128 * LDP];

    int tid = threadIdx.x, lane = tid & 63, w = tid >> 6;
    int quad = lane >> 4, n16 = lane & 15;
    int pr = blockIdx.x;  // pair index 0..7
    int h = blockIdx.y, b = blockIdx.z;
    int kh = h & 7;  // jnp.tile semantics: kv head = h % NKV
    int wrow = w * 32;  // wave's local row base in Ps

    const u16* Qg = qkv + (size_t)(b * SEQ) * QKV_N + h * 64;  // pre-scaled by 1/8
    const u16* Kg = qkv + (size_t)(b * SEQ) * QKV_N + (NHEAD + kh) * 64;
    const u16* Vg = vt + (size_t)((b * 8 + kh) * 64) * SEQ;

#pragma unroll
    for (int half = 0; half < 2; ++half) {
        int qb = half ? pr : (15 - pr);  // heavy q-block first
        int q0 = qb * 128;
        int rowbase = q0 + wrow;

        // Q fragments straight from global (B-operand layout: n16 = q-row, quad = d-chunk)
        bfrag qf[2][2];
#pragma unroll
        for (int ti = 0; ti < 2; ++ti)
#pragma unroll
            for (int ks = 0; ks < 2; ++ks)
                qf[ti][ks] = *(const bfrag*)(Qg + (size_t)(rowbase + ti * 16 + n16) * QKV_N + ks * 32 + quad * 8);

        ffrag o[2][4] = {};
        float lsum[2] = {0.f, 0.f};
        bfrag pf[4];

        int nkb = 2 * qb + 2;  // 64-key blocks covering keys <= q0+127
        stage64<64>(Kg, QKV_N, Ks[0]);
        __syncthreads();
        for (int i = 0; i <= nkb; ++i) {
            // prefetch: K one block ahead, V for the current S^T block (lag-1 consumer)
            if (i + 1 < nkb) stage64<64>(Kg + (size_t)((i + 1) * 64) * QKV_N, QKV_N, Ks[(i + 1) & 1]);
            if (i < nkb)     stage64<64>(Vg + i * 64, SEQ, Vs[i & 1]);
            if (i > 0) {
                // read P(i-1) into regs — written last iteration, no lgkm stall
#pragma unroll
                for (int ks = 0; ks < 2; ++ks)
#pragma unroll
                    for (int ti = 0; ti < 2; ++ti)
                        pf[ks * 2 + ti] = *(const bfrag*)(Ps + (wrow + ti * 16 + n16) * LDP + ks * 32 + quad * 8);
            }
            if (i < nkb) {
                if (i >= nkb - 2) st_phase<true>(i, rowbase, quad, n16, wrow, qf, Ks[i & 1], Ps, lsum);
                else              st_phase<false>(i, rowbase, quad, n16, wrow, qf, Ks[i & 1], Ps, lsum);
            }
            if (i > 0) pv_phase(pf, Vs[(i - 1) & 1], o, quad, n16);
            __syncthreads();  // drains prefetch (after compute) + guards buffer reuse
        }

        // reduce l across quads (lanes sharing n16), then redistribute to C-layout rows
#pragma unroll
        for (int ti = 0; ti < 2; ++ti) {
            lsum[ti] += __shfl_xor(lsum[ti], 16, 64);
            lsum[ti] += __shfl_xor(lsum[ti], 32, 64);
        }
#pragma unroll
        for (int ti = 0; ti < 2; ++ti) {
#pragma unroll
            for (int r = 0; r < 4; ++r) {
                float inv = 1.f / __shfl(lsum[ti], quad * 4 + r, 64);
                size_t rg = (size_t)(b * SEQ + rowbase + ti * 16 + quad * 4 + r) * DIMM + h * 64;
#pragma unroll
                for (int dj = 0; dj < 4; ++dj)
                    aout[rg + dj * 16 + n16] = f2bf(o[ti][dj][r] * inv);
            }
        }
    }
}

extern "C" void kernel_launch(void* const* d_in, const int* in_sizes, int n_in,
                              void* d_out, int out_size, void* d_ws, size_t ws_size,
                              hipStream_t stream) {
    const float* x    = (const float*)d_in[0];  // [4096][2048] fp32
    const float* Wqkv = (const float*)d_in[1];  // [3072][2048] fp32
    const float* Wout = (const float*)d_in[2];  // [2048][2048] fp32
    // d_in[3] = mask (fp32): causal applied analytically in-kernel
    float* out = (float*)d_out;                 // [4096][2048] fp32

    // Workspace (52 MiB), aliased by sequential lifetime:
    //   qkv      [0, 24 MiB)                — live GEMM1 .. attn
    //   xb/aout  [24, 40 MiB)               — xb: cvt..GEMM1; aout: attn..GEMM2
    //   R        [40, 52 MiB)               — Wqkvb: cvt..GEMM1; then vtb (4 MiB) +
    //                                          Woutb (8 MiB), both written post-GEMM1
    u16* qkv   = (u16*)d_ws;
    u16* xb    = qkv + (size_t)NQ * QKV_N;
    u16* aout  = xb;
    u16* R     = xb + (size_t)NQ * DIMM;
    u16* Wqkvb = R;
    u16* vtb   = R;
    u16* Woutb = R + (size_t)2 * NKV * 64 * SEQ;

    dim3 blk(256);
    cvt_xw<<<14336, blk, 0, stream>>>(x, xb, Wqkv, Wqkvb);
    gemm_nt<false, true><<<dim3(QKV_N / 128, NQ / 128), blk, 0, stream>>>(xb, Wqkvb, qkv, NQ, QKV_N, DIMM);
    post_gemm1<<<4608, blk, 0, stream>>>(qkv, vtb, Wout, Woutb);
    attn<<<dim3(8, NHEAD, 2), blk, 0, stream>>>(qkv, vtb, aout);
    gemm_nt<true, false><<<dim3(DIMM / 128, NQ / 128), blk, 0, stream>>>(aout, Woutb, out, NQ, DIMM, DIMM);
}